// Round 9
// baseline (491.725 us; speedup 1.0000x reference)
//
#include <hip/hip_runtime.h>
#include <hip/hip_bf16.h>
#include <cstdint>
#include <cstddef>

#define LRELU_ALPHA 0.2f
#define LOG2E 1.44269504088896f

typedef __attribute__((ext_vector_type(8))) short short8;
typedef __attribute__((ext_vector_type(4))) float f32x4;
typedef _Float16 h2v __attribute__((ext_vector_type(2)));

__device__ __forceinline__ unsigned short f2bf(float f) {
    unsigned int u = __float_as_uint(f);
    unsigned int r = (u + 0x7fffu + ((u >> 16) & 1u)) >> 16;   // RTN-even
    return (unsigned short)r;
}
__device__ __forceinline__ float bf2f(unsigned int lo16) {
    return __uint_as_float(lo16 << 16);
}
__device__ __forceinline__ unsigned int pk2(float a, float b) {
    return (unsigned int)f2bf(a) | ((unsigned int)f2bf(b) << 16);
}
__device__ __forceinline__ float fexp2(float x) {
#if __has_builtin(__builtin_amdgcn_exp2f)
    return __builtin_amdgcn_exp2f(x);
#else
    return __expf(x * 0.69314718056f);
#endif
}
__device__ __forceinline__ h2v pkrtz(float a, float b) {
#if __has_builtin(__builtin_amdgcn_cvt_pkrtz)
    auto r = __builtin_amdgcn_cvt_pkrtz(a, b);   // __fp16 ext_vector(2) on this clang
    union { decltype(r) i; h2v o; } u;
    u.i = r;
    return u.o;
#else
    h2v r; r.x = (_Float16)a; r.y = (_Float16)b; return r;
#endif
}
// pack_lo(a,b) = {lo16: a.lo16, hi16: b.lo16}; pack_hi = same for hi halves
__device__ __forceinline__ unsigned int pack_lo(unsigned int a, unsigned int b) {
#if __has_builtin(__builtin_amdgcn_perm)
    return __builtin_amdgcn_perm(a, b, 0x01000504u);
#else
    return (a & 0xffffu) | (b << 16);
#endif
}
__device__ __forceinline__ unsigned int pack_hi(unsigned int a, unsigned int b) {
#if __has_builtin(__builtin_amdgcn_perm)
    return __builtin_amdgcn_perm(a, b, 0x03020706u);
#else
    return (a >> 16) | (b & 0xffff0000u);
#endif
}
union U32H2 { unsigned int u; h2v h; };
__device__ __forceinline__ float dot2f(unsigned int a, h2v w, float acc) {
    U32H2 c; c.u = a;
#if __has_builtin(__builtin_amdgcn_fdot2)
    return __builtin_amdgcn_fdot2(c.h, w, acc, false);
#else
    return acc + (float)c.h.x * (float)w.x + (float)c.h.y * (float)w.y;
#endif
}

// ---------------- CSR build (padded to x8 per row) ----------------
// Ledger rule (R5/R6/R7): return-atomics may feed COALESCED stores (fast, R6), never
// scattered stores (137 us, R5/R7). So: hist owns the return-atomic (rank, coalesced);
// scatter is atomic-free: pos = base8[rep][row] + rank[e]. ILP-8 per thread.
// counts 8-way XCD-replicated (rep=blockIdx&7; round-robin XCD dispatch keeps replica
// lines XCD-local). Identical e->block mapping in hist and scatter. Speed-only heuristic.

__global__ void hist8_k(const int* __restrict__ ei, int* __restrict__ counts8,
                        int* __restrict__ rank,
                        float* __restrict__ sdA, float* __restrict__ sdB,
                        float* __restrict__ sdC, unsigned int* __restrict__ hW,
                        int N_, int E_) {
    int rep = blockIdx.x & 7;
    int base = (blockIdx.x * 256 + threadIdx.x) * 8;
    int* cnt = counts8 + (size_t)rep * N_;
    if (base + 8 <= E_) {
        int4 a = *(const int4*)&ei[base];
        int4 b = *(const int4*)&ei[base + 4];
        int rk[8];
        rk[0] = atomicAdd(&cnt[a.x], 1);
        rk[1] = atomicAdd(&cnt[a.y], 1);
        rk[2] = atomicAdd(&cnt[a.z], 1);
        rk[3] = atomicAdd(&cnt[a.w], 1);
        rk[4] = atomicAdd(&cnt[b.x], 1);
        rk[5] = atomicAdd(&cnt[b.y], 1);
        rk[6] = atomicAdd(&cnt[b.z], 1);
        rk[7] = atomicAdd(&cnt[b.w], 1);
        *(int4*)&rank[base]     = make_int4(rk[0], rk[1], rk[2], rk[3]);
        *(int4*)&rank[base + 4] = make_int4(rk[4], rk[5], rk[6], rk[7]);
    } else if (base < E_) {
        for (int j = 0; j < 8 && base + j < E_; j++)
            rank[base + j] = atomicAdd(&cnt[ei[base + j]], 1);
    }
    if (blockIdx.x == 0) {
        int t = threadIdx.x;
        if (t < 4) { sdA[N_ * 4 + t] = -1e30f; sdB[N_ * 4 + t] = -1e30f; }
        if (t == 4) sdC[N_] = -1e30f;
        if (t >= 32 && t < 64)  hW[(size_t)N_ * 32 + (t - 32)] = 0u;   // DHT=64 dummy row
        if (t >= 64 && t < 128) hW[(size_t)N_ * 64 + (t - 64)] = 0u;   // DHT=128 dummy row
    }
}

__global__ void scan_block_k(const int* __restrict__ counts8, int* __restrict__ tmp,
                             int* __restrict__ bsum, int n) {
    __shared__ int s[256];
    int i = blockIdx.x * 256 + threadIdx.x;
    int v = 0;
    if (i < n) {
        int c = 0;
        #pragma unroll
        for (int r = 0; r < 8; r++) c += counts8[(size_t)r * n + i];
        v = (c + 7) & ~7;   // round rows up to x8
    }
    s[threadIdx.x] = v;
    __syncthreads();
    for (int d = 1; d < 256; d <<= 1) {
        int t_ = (threadIdx.x >= d) ? s[threadIdx.x - d] : 0;
        __syncthreads();
        s[threadIdx.x] += t_;
        __syncthreads();
    }
    if (i < n) tmp[i] = s[threadIdx.x];
    if (threadIdx.x == 255) bsum[blockIdx.x] = s[255];
}

__global__ void scan_sums_k(int* bsum, int nb) {
    __shared__ int s[512];
    int v = ((int)threadIdx.x < nb) ? bsum[threadIdx.x] : 0;
    s[threadIdx.x] = v;
    __syncthreads();
    for (int d = 1; d < 512; d <<= 1) {
        int t_ = ((int)threadIdx.x >= d) ? s[threadIdx.x - d] : 0;
        __syncthreads();
        s[threadIdx.x] += t_;
        __syncthreads();
    }
    if ((int)threadIdx.x < nb) bsum[threadIdx.x] = s[threadIdx.x] - v;  // exclusive
}

// off[i+1], per-replica scatter bases, and scol pad-gap fill (only the <=7 pad slots/row)
__global__ void finalize_k(const int* __restrict__ tmp, const int* __restrict__ bsum,
                           const int* __restrict__ counts8, int* __restrict__ base8,
                           int* __restrict__ off, int* __restrict__ scol, int N_, int n) {
    int i = blockIdx.x * 256 + threadIdx.x;
    if (i < n) {
        int end = tmp[i] + bsum[blockIdx.x];
        off[i + 1] = end;
        int c[8], cnt = 0;
        #pragma unroll
        for (int r = 0; r < 8; r++) { c[r] = counts8[(size_t)r * n + i]; cnt += c[r]; }
        int padded = (cnt + 7) & ~7;
        int pos = end - padded;   // = off[i] (padded sizes are contiguous)
        #pragma unroll
        for (int r = 0; r < 8; r++) { base8[(size_t)r * n + i] = pos; pos += c[r]; }
        // pos == start + cnt; fill pad gap with dummy node
        for (; pos < end; pos++) scol[pos] = N_;
    }
    if (i == 0) off[0] = 0;
}

__global__ void scatter8_k(const int* __restrict__ ei, const int* __restrict__ rank,
                           const int* __restrict__ base8, int* __restrict__ scol,
                           int N_, int E_) {
    int rep = blockIdx.x & 7;   // SAME e->block mapping as hist8_k
    int base = (blockIdx.x * 256 + threadIdx.x) * 8;
    const int* cb = base8 + (size_t)rep * N_;
    if (base + 8 <= E_) {
        int4 a   = *(const int4*)&ei[base];
        int4 b   = *(const int4*)&ei[base + 4];
        int4 ra  = *(const int4*)&rank[base];
        int4 rb  = *(const int4*)&rank[base + 4];
        int4 ca  = *(const int4*)&ei[E_ + base];
        int4 cb4 = *(const int4*)&ei[E_ + base + 4];
        scol[cb[a.x] + ra.x] = ca.x;
        scol[cb[a.y] + ra.y] = ca.y;
        scol[cb[a.z] + ra.z] = ca.z;
        scol[cb[a.w] + ra.w] = ca.w;
        scol[cb[b.x] + rb.x] = cb4.x;
        scol[cb[b.y] + rb.y] = cb4.y;
        scol[cb[b.z] + rb.z] = cb4.z;
        scol[cb[b.w] + rb.w] = cb4.w;
    } else if (base < E_) {
        for (int j = 0; j < 8 && base + j < E_; j++) {
            int r = ei[base + j];
            scol[cb[r] + rank[base + j]] = ei[E_ + base + j];
        }
    }
}

// ---------------- weight repack: all matrices -> WT[n][k] bf16, score-augmented ---------
// W1/W2: 144 cols = 128 Whid-cat cols + 8 a-channel cols (x LOG2E) + 8 zero cols.
// W3:     80 cols =  64 Wout cols     + 2 a_out cols    (x LOG2E) + 14 zero cols.
// Score channel c = hd*2 + side  ->  extra col 128+c (resp. 64+c).

__global__ void repack_all(const float* __restrict__ Win, const float* __restrict__ Whid,
                           const float* __restrict__ ahid, const float* __restrict__ Wout,
                           const float* __restrict__ aout,
                           unsigned short* __restrict__ W0, unsigned short* __restrict__ W1,
                           unsigned short* __restrict__ W2, unsigned short* __restrict__ W3) {
    int i = blockIdx.x * 256 + threadIdx.x;
    if (i < 16384) {                       // Win [128][128], HD=1
        int n = i >> 7, k = i & 127;
        W0[i] = f2bf(Win[k * 128 + n]);
    } else if (i < 16384 + 2 * 18432) {    // W1/W2: [144][128]
        int j = i - 16384;
        int l = j / 18432;
        int jj = j - l * 18432;
        int n = jj >> 7, k = jj & 127;
        float v;
        if (n < 128) {
            int hd = n >> 5, c = n & 31;
            v = Whid[(size_t)l * 16384 + (hd * 128 + k) * 32 + c];
        } else if (n < 136) {
            int ch = n - 128;               // ch = hd*2+side
            v = ahid[((size_t)l * 8 + ch) * 128 + k] * LOG2E;
        } else {
            v = 0.f;
        }
        (l ? W2 : W1)[jj] = f2bf(v);
    } else if (i < 16384 + 2 * 18432 + 10240) {   // W3: [80][128]
        int j = i - (16384 + 2 * 18432);
        int n = j >> 7, k = j & 127;
        float v;
        if (n < 64)       v = Wout[k * 64 + n];
        else if (n < 66)  v = aout[(n - 64) * 128 + k] * LOG2E;
        else              v = 0.f;
        W3[j] = f2bf(v);
    }
}

// ---------------- MFMA GEMM: Y[n,0:KJ] = act(X @ W + bias); cols [KJ,KJ+2*SC_H) = scores
// KJA = KJ (+16 if SC_H>0). Score tile is the last MFMA column tile; its channel c=l16
// writes (c&1 ? sdst : ssrc)[row*SC_H + (c>>1)]  (a-cols pre-scaled by LOG2E in repack).
// C/D layout: col=lane&15, row=(lane>>4)*4+reg.

template <int KJ, int KJA, bool ELU_ACT, bool BIAS, int OUTM, bool ABF16, int SC_H>
__global__ __launch_bounds__(256) void gemm_mfma(const void* __restrict__ Xv,
                                                 const unsigned short* __restrict__ WT,
                                                 const float* __restrict__ bias,
                                                 void* __restrict__ Yv,
                                                 float* __restrict__ ssn,
                                                 float* __restrict__ sdn, int nRows) {
    constexpr int NT = KJA / 16;     // all MFMA col tiles
    constexpr int NTS = KJ / 16;     // stored (hW) col tiles
    constexpr int WS = 136;
    __shared__ unsigned short sWT[KJA * WS];
    int t = threadIdx.x;
    for (int i = t; i < KJA * 16; i += 256) {
        int n = i >> 4, k8 = i & 15;
        uint4 v = *(const uint4*)&WT[n * 128 + k8 * 8];
        *(uint4*)&sWT[n * WS + k8 * 8] = v;
    }
    __syncthreads();

    int lane = t & 63;
    int wv = t >> 6;
    int m0 = blockIdx.x * 128 + wv * 32;
    int l16 = lane & 15;
    int q4 = lane >> 4;

    short8 afr[4][2];
    #pragma unroll
    for (int rt = 0; rt < 2; rt++) {
        int row = m0 + rt * 16 + l16;
        bool vr = row < nRows;
        if (ABF16) {
            const unsigned int* xp = (const unsigned int*)Xv + (size_t)row * 64 + q4 * 4;
            #pragma unroll
            for (int kk = 0; kk < 4; kk++) {
                uint4 u = make_uint4(0u, 0u, 0u, 0u);
                if (vr) u = *(const uint4*)(xp + kk * 16);
                afr[kk][rt] = *(short8*)&u;
            }
        } else {
            const float* xp = (const float*)Xv + (size_t)row * 128 + q4 * 8;
            #pragma unroll
            for (int kk = 0; kk < 4; kk++) {
                float4 a0 = make_float4(0.f, 0.f, 0.f, 0.f), a1 = a0;
                if (vr) {
                    a0 = *(const float4*)(xp + kk * 32);
                    a1 = *(const float4*)(xp + kk * 32 + 4);
                }
                unsigned int u[4];
                u[0] = pk2(a0.x, a0.y); u[1] = pk2(a0.z, a0.w);
                u[2] = pk2(a1.x, a1.y); u[3] = pk2(a1.z, a1.w);
                afr[kk][rt] = *(short8*)u;
            }
        }
    }

    f32x4 acc[2][NT] = {};
    #pragma unroll
    for (int kk = 0; kk < 4; kk++) {
        #pragma unroll
        for (int ct = 0; ct < NT; ct++) {
            int n = ct * 16 + l16;
            short8 bf = *(const short8*)&sWT[n * WS + kk * 32 + q4 * 8];
            #pragma unroll
            for (int rt = 0; rt < 2; rt++)
                acc[rt][ct] = __builtin_amdgcn_mfma_f32_16x16x32_bf16(afr[kk][rt], bf, acc[rt][ct], 0, 0, 0);
        }
    }

    #pragma unroll
    for (int rt = 0; rt < 2; rt++) {
        #pragma unroll
        for (int q = 0; q < 4; q++) {
            int row = m0 + rt * 16 + q4 * 4 + q;
            if (row >= nRows) continue;
            #pragma unroll
            for (int ct = 0; ct < NTS; ct++) {
                int colc = ct * 16 + l16;
                float v = acc[rt][ct][q];
                if (BIAS) v += bias[colc];
                if (ELU_ACT) v = v > 0.f ? v : (__expf(v) - 1.f);
                if (OUTM == 1) {
                    ((unsigned short*)Yv)[(size_t)row * KJ + colc] = f2bf(v);
                } else if (OUTM == 2) {
                    union { _Float16 hf; unsigned short us; } cv;
                    cv.hf = (_Float16)v;
                    ((unsigned short*)Yv)[(size_t)row * KJ + colc] = cv.us;
                } else {
                    ((float*)Yv)[(size_t)row * KJ + colc] = v;
                }
            }
            if (SC_H > 0) {
                if (l16 < 2 * SC_H) {
                    float v = acc[rt][NT - 1][q];    // raw linear score (a pre-scaled)
                    float* dst = (l16 & 1) ? sdn : ssn;
                    dst[row * SC_H + (l16 >> 1)] = v;
                }
            }
        }
    }
}

// ---------------- edge pass, feature-split (DHT=128, H=4) ----------------
// half = (bid&7)>>2 binds feature half to an XCD QUAD via round-robin dispatch:
// XCDs 0-3 gather cols [0,64), XCDs 4-7 cols [64,128). Each 12.8MB half-table is then
// fetched by only 4 XCDs -> duplication floor 205MB -> ~102MB. Score/exp/den work is
// duplicated per half (VALU has headroom); output uints disjoint. Speed heuristic only.

template <bool ELU_ACT>
__global__ __launch_bounds__(256) void edge_agg_half(const unsigned int* __restrict__ hW2,
                                                     const float* __restrict__ ssrc,
                                                     const float* __restrict__ sdst,
                                                     const int* __restrict__ off,
                                                     const int* __restrict__ scol,
                                                     unsigned int* __restrict__ outv,
                                                     int nRowBlk, int nRows) {
    constexpr int H = 4;
    int lane = threadIdx.x & 63;
    int sub = lane & 15;
    int g = lane >> 4;
    int wv = threadIdx.x >> 6;
    int bid = blockIdx.x;
    int half = (bid & 7) >> 2;
    int rowblk = (bid >> 3) * 4 + (bid & 3);
    if (rowblk >= nRowBlk) return;
    int r = __builtin_amdgcn_readfirstlane(rowblk * 4 + wv);
    if (r >= nRows) return;
    int begin = off[r], end = off[r + 1];

    int head = half * 2 + (sub >> 3);        // feats half*64 + sub*4 .. +3 -> head
    float ssl = ssrc[r * H + head];
    const unsigned int* hWh = hW2 + half * 32 + sub * 2;

    float acc[4] = {};
    float den = 0.f;

    for (int i = begin; i < end; i += 8) {
        int2 cc = *(const int2*)&scol[i + 2 * g];
        int cA = cc.x, cB = cc.y;
        float sdA = sdst[cA * H + head];
        float sdB = sdst[cB * H + head];
        uint2 hA = *(const uint2*)&hWh[cA * 64];
        uint2 hB = *(const uint2*)&hWh[cB * 64];
        float lgA = ssl + sdA;
        float wA = fexp2(fmaxf(lgA, LRELU_ALPHA * lgA));
        float lgB = ssl + sdB;
        float wB = fexp2(fmaxf(lgB, LRELU_ALPHA * lgB));
        den += wA + wB;
        h2v w2 = pkrtz(wA, wB);
        acc[0] = dot2f(pack_lo(hA.x, hB.x), w2, acc[0]);
        acc[1] = dot2f(pack_hi(hA.x, hB.x), w2, acc[1]);
        acc[2] = dot2f(pack_lo(hA.y, hB.y), w2, acc[2]);
        acc[3] = dot2f(pack_hi(hA.y, hB.y), w2, acc[3]);
    }

    #pragma unroll
    for (int s = 16; s < 64; s <<= 1) {
        den += __shfl_xor(den, s);
        #pragma unroll
        for (int p = 0; p < 4; p++) acc[p] += __shfl_xor(acc[p], s);
    }
    float inv = den > 0.f ? 1.f / den : 0.f;

    if (g < 2) {
        float v0 = acc[2 * g] * inv, v1 = acc[2 * g + 1] * inv;
        if (ELU_ACT) {
            v0 = v0 > 0.f ? v0 : (__expf(v0) - 1.f);
            v1 = v1 > 0.f ? v1 : (__expf(v1) - 1.f);
        }
        outv[(size_t)r * 64 + half * 32 + sub * 2 + g] = pk2(v0, v1);
    }
}

// ---------------- edge pass: fp16 hW + v_dot2 aggregation (DHT=64 output layer) --------

template <int DHT, int H, bool ELU_ACT, bool BF16O>
__global__ __launch_bounds__(256) void edge_agg_v(const unsigned int* __restrict__ hW2,
                                                  const float* __restrict__ ssrc,
                                                  const float* __restrict__ sdst,
                                                  const int* __restrict__ off,
                                                  const int* __restrict__ scol,
                                                  void* __restrict__ outv, int nRows) {
    constexpr int FPL = DHT / 16;   // features per lane
    constexpr int UPL = FPL / 2;    // packed uints per lane
    int lane = threadIdx.x & 63;
    int sub = lane & 15;
    int g = lane >> 4;
    int wv = threadIdx.x >> 6;
    int r = __builtin_amdgcn_readfirstlane(blockIdx.x * 4 + wv);
    if (r >= nRows) return;
    int begin = off[r], end = off[r + 1];

    int head = (H == 4) ? (sub >> 2) : 0;
    float ssl = ssrc[r * H + head];

    float acc[FPL] = {};
    float den = 0.f;

    for (int i = begin; i < end; i += 8) {
        int2 cc = *(const int2*)&scol[i + 2 * g];
        int cA = cc.x, cB = cc.y;
        float sdA = sdst[cA * H + head];
        float sdB = sdst[cB * H + head];
        unsigned int hA[UPL], hB[UPL];
        int oA = cA * (DHT / 2) + sub * UPL;
        int oB = cB * (DHT / 2) + sub * UPL;
        if (UPL == 4) {
            *(uint4*)hA = *(const uint4*)&hW2[oA];
            *(uint4*)hB = *(const uint4*)&hW2[oB];
        } else {
            *(uint2*)hA = *(const uint2*)&hW2[oA];
            *(uint2*)hB = *(const uint2*)&hW2[oB];
        }
        float lgA = ssl + sdA;
        float wA = fexp2(fmaxf(lgA, LRELU_ALPHA * lgA));
        float lgB = ssl + sdB;
        float wB = fexp2(fmaxf(lgB, LRELU_ALPHA * lgB));
        den += wA + wB;
        h2v w2 = pkrtz(wA, wB);
        #pragma unroll
        for (int q = 0; q < UPL; q++) {
            acc[2 * q]     = dot2f(pack_lo(hA[q], hB[q]), w2, acc[2 * q]);
            acc[2 * q + 1] = dot2f(pack_hi(hA[q], hB[q]), w2, acc[2 * q + 1]);
        }
    }

    #pragma unroll
    for (int s = 16; s < 64; s <<= 1) {
        den += __shfl_xor(den, s);
        #pragma unroll
        for (int p = 0; p < FPL; p++) acc[p] += __shfl_xor(acc[p], s);
    }
    float inv = den > 0.f ? 1.f / den : 0.f;

    float v[FPL];
    #pragma unroll
    for (int p = 0; p < FPL; p++) {
        float tv = acc[p] * inv;
        if (ELU_ACT) tv = tv > 0.f ? tv : (__expf(tv) - 1.f);
        v[p] = tv;
    }

    if (DHT == 128) {
        if (BF16O)
            ((unsigned int*)outv)[(size_t)r * 64 + sub * 4 + g] = pk2(v[2 * g], v[2 * g + 1]);
        else
            *(float2*)&((float*)outv)[(size_t)r * 128 + sub * 8 + 2 * g] =
                make_float2(v[2 * g], v[2 * g + 1]);
    } else {
        ((float*)outv)[(size_t)r * DHT + sub * FPL + g] = v[g];
    }
}

// ---------------- launcher ----------------

extern "C" void kernel_launch(void* const* d_in, const int* in_sizes, int n_in,
                              void* d_out, int out_size, void* d_ws, size_t ws_size,
                              hipStream_t stream) {
    const float* x    = (const float*)d_in[0];
    const int*   ei   = (const int*)d_in[1];
    const float* Win  = (const float*)d_in[2];
    const float* bin  = (const float*)d_in[3];
    const float* ahid = (const float*)d_in[4];
    const float* Whid = (const float*)d_in[5];
    const float* aout = (const float*)d_in[6];
    const float* Wout = (const float*)d_in[7];
    float* out = (float*)d_out;

    const int N_ = in_sizes[0] / 128;
    const int E_ = in_sizes[1] / 2;

    char* p = (char*)d_ws;
    auto alloc = [&](size_t bytes) {
        char* q = p;
        p += (bytes + 511) & ~(size_t)511;
        return q;
    };
    int* counts8 = (int*)alloc((size_t)N_ * 8 * 4);
    int* base8   = (int*)alloc((size_t)N_ * 8 * 4);
    int* rank    = (int*)alloc((size_t)(E_ + 8) * 4);
    int* tmp     = (int*)alloc((size_t)N_ * 4);
    int* off     = (int*)alloc((size_t)(N_ + 1) * 4);
    int* bsum    = (int*)alloc(4096);
    int* scol    = (int*)alloc((size_t)(E_ + 8 * N_ + 64) * 4);   // padded CSR
    float* ssrcA = (float*)alloc((size_t)(N_ + 1) * 4 * 4);
    float* sdstA = (float*)alloc((size_t)(N_ + 1) * 4 * 4);
    float* ssrcB = (float*)alloc((size_t)(N_ + 1) * 4 * 4);
    float* sdstB = (float*)alloc((size_t)(N_ + 1) * 4 * 4);
    float* ssrcC = (float*)alloc((size_t)(N_ + 1) * 4);
    float* sdstC = (float*)alloc((size_t)(N_ + 1) * 4);
    unsigned int* hb  = (unsigned int*)alloc((size_t)N_ * 64 * 4);        // h  bf16 packed
    unsigned int* hWb = (unsigned int*)alloc((size_t)(N_ + 1) * 64 * 4);  // hW fp16 packed (+dummy row)
    unsigned short* WT0 = (unsigned short*)alloc(128 * 128 * 2);
    unsigned short* WT1 = (unsigned short*)alloc(144 * 128 * 2);
    unsigned short* WT2 = (unsigned short*)alloc(144 * 128 * 2);
    unsigned short* WT3 = (unsigned short*)alloc(80 * 128 * 2);

    int NB  = (N_ + 255) / 256;
    int EB8 = (E_ + 2047) / 2048;    // ILP-8: 8 edges per thread
    int RT  = (N_ + 127) / 128;
    int NW  = (N_ + 3) / 4;
    int GH  = 8 * ((NW + 3) / 4);    // feature-split grid: 2 halves x 4-block quads

    // CSR by destination (= edge_index[0], the softmax segment key), rows padded to x8
    (void)hipMemsetAsync(counts8, 0, (size_t)N_ * 8 * 4, stream);
    hist8_k<<<EB8, 256, 0, stream>>>(ei, counts8, rank, sdstA, sdstB, sdstC, hWb, N_, E_);
    scan_block_k<<<NB, 256, 0, stream>>>(counts8, tmp, bsum, N_);
    scan_sums_k<<<1, 512, 0, stream>>>(bsum, NB);
    finalize_k<<<NB, 256, 0, stream>>>(tmp, bsum, counts8, base8, off, scol, N_, N_);
    scatter8_k<<<EB8, 256, 0, stream>>>(ei, rank, base8, scol, N_, E_);

    // all weight repacks in one launch (a-vectors augmented as extra GEMM columns)
    repack_all<<<248, 256, 0, stream>>>(Win, Whid, ahid, Wout, aout, WT0, WT1, WT2, WT3);

    // input linear + ELU -> h0 bf16
    gemm_mfma<128, 128, true, true, 1, false, 0><<<RT, 256, 0, stream>>>(
        x, WT0, bin, hb, nullptr, nullptr, N_);

    // hidden layer 1: [hW0 | scoresA] = h0 @ [Wcat0 | a0] ; aggregate -> h1 bf16
    gemm_mfma<128, 144, false, false, 2, true, 4><<<RT, 256, 0, stream>>>(
        hb, WT1, nullptr, hWb, ssrcA, sdstA, N_);
    edge_agg_half<true><<<GH, 256, 0, stream>>>(
        hWb, ssrcA, sdstA, off, scol, hb, NW, N_);

    // hidden layer 2: [hW1 | scoresB] = h1 @ [Wcat1 | a1] ; aggregate -> h2 bf16
    gemm_mfma<128, 144, false, false, 2, true, 4><<<RT, 256, 0, stream>>>(
        hb, WT2, nullptr, hWb, ssrcB, sdstB, N_);
    edge_agg_half<true><<<GH, 256, 0, stream>>>(
        hWb, ssrcB, sdstB, off, scol, hb, NW, N_);

    // output layer: [hW2 | scoresC] = h2 @ [Wout | a_out] ; aggregate -> out fp32
    gemm_mfma<64, 80, false, false, 2, true, 1><<<RT, 256, 0, stream>>>(
        hb, WT3, nullptr, hWb, ssrcC, sdstC, N_);
    edge_agg_v<64, 1, false, false><<<NW, 256, 0, stream>>>(
        hWb, ssrcC, sdstC, off, scol, out, N_);
}

// Round 10
// 456.479 us; speedup vs baseline: 1.0772x; 1.0772x over previous
//
#include <hip/hip_runtime.h>
#include <hip/hip_bf16.h>
#include <cstdint>
#include <cstddef>

#define LRELU_ALPHA 0.2f
#define LOG2E 1.44269504088896f

typedef __attribute__((ext_vector_type(8))) short short8;
typedef __attribute__((ext_vector_type(4))) float f32x4;
typedef _Float16 h2v __attribute__((ext_vector_type(2)));

__device__ __forceinline__ unsigned short f2bf(float f) {
    unsigned int u = __float_as_uint(f);
    unsigned int r = (u + 0x7fffu + ((u >> 16) & 1u)) >> 16;   // RTN-even
    return (unsigned short)r;
}
__device__ __forceinline__ float bf2f(unsigned int lo16) {
    return __uint_as_float(lo16 << 16);
}
__device__ __forceinline__ unsigned int pk2(float a, float b) {
    return (unsigned int)f2bf(a) | ((unsigned int)f2bf(b) << 16);
}
__device__ __forceinline__ float fexp2(float x) {
#if __has_builtin(__builtin_amdgcn_exp2f)
    return __builtin_amdgcn_exp2f(x);
#else
    return __expf(x * 0.69314718056f);
#endif
}
__device__ __forceinline__ h2v pkrtz(float a, float b) {
#if __has_builtin(__builtin_amdgcn_cvt_pkrtz)
    auto r = __builtin_amdgcn_cvt_pkrtz(a, b);   // __fp16 ext_vector(2) on this clang
    union { decltype(r) i; h2v o; } u;
    u.i = r;
    return u.o;
#else
    h2v r; r.x = (_Float16)a; r.y = (_Float16)b; return r;
#endif
}
// pack_lo(a,b) = {lo16: a.lo16, hi16: b.lo16}; pack_hi = same for hi halves
__device__ __forceinline__ unsigned int pack_lo(unsigned int a, unsigned int b) {
#if __has_builtin(__builtin_amdgcn_perm)
    return __builtin_amdgcn_perm(a, b, 0x01000504u);
#else
    return (a & 0xffffu) | (b << 16);
#endif
}
__device__ __forceinline__ unsigned int pack_hi(unsigned int a, unsigned int b) {
#if __has_builtin(__builtin_amdgcn_perm)
    return __builtin_amdgcn_perm(a, b, 0x03020706u);
#else
    return (a >> 16) | (b & 0xffff0000u);
#endif
}
union U32H2 { unsigned int u; h2v h; };
__device__ __forceinline__ float dot2f(unsigned int a, h2v w, float acc) {
    U32H2 c; c.u = a;
#if __has_builtin(__builtin_amdgcn_fdot2)
    return __builtin_amdgcn_fdot2(c.h, w, acc, false);
#else
    return acc + (float)c.h.x * (float)w.x + (float)c.h.y * (float)w.y;
#endif
}

// ---------------- CSR build (padded to x8 per row) ----------------
// Ledger (R5/R6/R7): return-atomics may feed COALESCED stores, never scattered stores.
// hist owns the return-atomic (rank, coalesced); scatter is atomic-free.
// Ledger (R9): feature-split fails — half-tables (12.8MB) exceed 4MB/XCD L2, so
// cross-XCD duplication persists; edge gather FETCH ~227MB @ ~3.3TB/s is the floor.

// fused: histogram (blocks [0,EB8)) + weight repack (blocks [EB8,EB8+248)).
// Repack: W1/W2 144 cols = 128 Whid-cat + 8 a-chan (xLOG2E) + 8 zero; W3 80 cols.
__global__ void hist_repack_k(const int* __restrict__ ei, int* __restrict__ counts8,
                              int* __restrict__ rank,
                              float* __restrict__ sdA, float* __restrict__ sdB,
                              float* __restrict__ sdC, unsigned int* __restrict__ hW,
                              const float* __restrict__ Win, const float* __restrict__ Whid,
                              const float* __restrict__ ahid, const float* __restrict__ Wout,
                              const float* __restrict__ aout,
                              unsigned short* __restrict__ W0, unsigned short* __restrict__ W1,
                              unsigned short* __restrict__ W2, unsigned short* __restrict__ W3,
                              int N_, int E_, int EB8) {
    int bid = blockIdx.x;
    if (bid < EB8) {
        int rep = bid & 7;
        int base = (bid * 256 + threadIdx.x) * 8;
        int* cnt = counts8 + (size_t)rep * N_;
        if (base + 8 <= E_) {
            int4 a = *(const int4*)&ei[base];
            int4 b = *(const int4*)&ei[base + 4];
            int rk[8];
            rk[0] = atomicAdd(&cnt[a.x], 1);
            rk[1] = atomicAdd(&cnt[a.y], 1);
            rk[2] = atomicAdd(&cnt[a.z], 1);
            rk[3] = atomicAdd(&cnt[a.w], 1);
            rk[4] = atomicAdd(&cnt[b.x], 1);
            rk[5] = atomicAdd(&cnt[b.y], 1);
            rk[6] = atomicAdd(&cnt[b.z], 1);
            rk[7] = atomicAdd(&cnt[b.w], 1);
            *(int4*)&rank[base]     = make_int4(rk[0], rk[1], rk[2], rk[3]);
            *(int4*)&rank[base + 4] = make_int4(rk[4], rk[5], rk[6], rk[7]);
        } else if (base < E_) {
            for (int j = 0; j < 8 && base + j < E_; j++)
                rank[base + j] = atomicAdd(&cnt[ei[base + j]], 1);
        }
        if (bid == 0) {
            int t = threadIdx.x;
            if (t < 4) { sdA[N_ * 4 + t] = -1e30f; sdB[N_ * 4 + t] = -1e30f; }
            if (t == 4) sdC[N_] = -1e30f;
            if (t >= 32 && t < 64)  hW[(size_t)N_ * 32 + (t - 32)] = 0u;   // DHT=64 dummy
            if (t >= 64 && t < 128) hW[(size_t)N_ * 64 + (t - 64)] = 0u;   // DHT=128 dummy
        }
    } else {
        int i = (bid - EB8) * 256 + threadIdx.x;
        if (i < 16384) {                       // Win [128][128], HD=1
            int n = i >> 7, k = i & 127;
            W0[i] = f2bf(Win[k * 128 + n]);
        } else if (i < 16384 + 2 * 18432) {    // W1/W2: [144][128]
            int j = i - 16384;
            int l = j / 18432;
            int jj = j - l * 18432;
            int n = jj >> 7, k = jj & 127;
            float v;
            if (n < 128) {
                int hd = n >> 5, c = n & 31;
                v = Whid[(size_t)l * 16384 + (hd * 128 + k) * 32 + c];
            } else if (n < 136) {
                int ch = n - 128;               // ch = hd*2+side
                v = ahid[((size_t)l * 8 + ch) * 128 + k] * LOG2E;
            } else {
                v = 0.f;
            }
            (l ? W2 : W1)[jj] = f2bf(v);
        } else if (i < 16384 + 2 * 18432 + 10240) {   // W3: [80][128]
            int j = i - (16384 + 2 * 18432);
            int n = j >> 7, k = j & 127;
            float v;
            if (n < 64)       v = Wout[k * 64 + n];
            else if (n < 66)  v = aout[(n - 64) * 128 + k] * LOG2E;
            else              v = 0.f;
            W3[j] = f2bf(v);
        }
    }
}

__global__ void scan_sums_k(int* bsum, int nb) {
    __shared__ int s[512];
    int v = ((int)threadIdx.x < nb) ? bsum[threadIdx.x] : 0;
    s[threadIdx.x] = v;
    __syncthreads();
    for (int d = 1; d < 512; d <<= 1) {
        int t_ = ((int)threadIdx.x >= d) ? s[threadIdx.x - d] : 0;
        __syncthreads();
        s[threadIdx.x] += t_;
        __syncthreads();
    }
    if ((int)threadIdx.x < nb) bsum[threadIdx.x] = s[threadIdx.x] - v;  // exclusive
}

// off[i+1], per-replica scatter bases, and scol pad-gap fill (only the <=7 pad slots/row)
__global__ void finalize_k(const int* __restrict__ tmp, const int* __restrict__ bsum,
                           const int* __restrict__ counts8, int* __restrict__ base8,
                           int* __restrict__ off, int* __restrict__ scol, int N_, int n) {
    int i = blockIdx.x * 256 + threadIdx.x;
    if (i < n) {
        int end = tmp[i] + bsum[blockIdx.x];
        off[i + 1] = end;
        int c[8], cnt = 0;
        #pragma unroll
        for (int r = 0; r < 8; r++) { c[r] = counts8[(size_t)r * n + i]; cnt += c[r]; }
        int padded = (cnt + 7) & ~7;
        int pos = end - padded;   // = off[i] (padded sizes are contiguous)
        #pragma unroll
        for (int r = 0; r < 8; r++) { base8[(size_t)r * n + i] = pos; pos += c[r]; }
        // pos == start + cnt; fill pad gap with dummy node
        for (; pos < end; pos++) scol[pos] = N_;
    }
    if (i == 0) off[0] = 0;
}

__global__ void scatter8_k(const int* __restrict__ ei, const int* __restrict__ rank,
                           const int* __restrict__ base8, int* __restrict__ scol,
                           int N_, int E_) {
    int rep = blockIdx.x & 7;   // SAME e->block mapping as hist blocks of hist_repack_k
    int base = (blockIdx.x * 256 + threadIdx.x) * 8;
    const int* cb = base8 + (size_t)rep * N_;
    if (base + 8 <= E_) {
        int4 a   = *(const int4*)&ei[base];
        int4 b   = *(const int4*)&ei[base + 4];
        int4 ra  = *(const int4*)&rank[base];
        int4 rb  = *(const int4*)&rank[base + 4];
        int4 ca  = *(const int4*)&ei[E_ + base];
        int4 cb4 = *(const int4*)&ei[E_ + base + 4];
        scol[cb[a.x] + ra.x] = ca.x;
        scol[cb[a.y] + ra.y] = ca.y;
        scol[cb[a.z] + ra.z] = ca.z;
        scol[cb[a.w] + ra.w] = ca.w;
        scol[cb[b.x] + rb.x] = cb4.x;
        scol[cb[b.y] + rb.y] = cb4.y;
        scol[cb[b.z] + rb.z] = cb4.z;
        scol[cb[b.w] + rb.w] = cb4.w;
    } else if (base < E_) {
        for (int j = 0; j < 8 && base + j < E_; j++) {
            int r = ei[base + j];
            scol[cb[r] + rank[base + j]] = ei[E_ + base + j];
        }
    }
}

// ---------------- MFMA GEMM body: Y[n,0:KJ] = act(X @ W + bias); last tile = scores ----
// C/D layout: col=lane&15, row=(lane>>4)*4+reg.

template <int KJ, int KJA, bool ELU_ACT, bool BIAS, int OUTM, bool ABF16, int SC_H>
__device__ __forceinline__ void gemm_body(const void* __restrict__ Xv,
                                          const unsigned short* __restrict__ WT,
                                          const float* __restrict__ bias,
                                          void* __restrict__ Yv,
                                          float* __restrict__ ssn,
                                          float* __restrict__ sdn, int nRows,
                                          int bid, unsigned short* sWT) {
    constexpr int NT = KJA / 16;     // all MFMA col tiles
    constexpr int NTS = KJ / 16;     // stored (hW) col tiles
    constexpr int WS = 136;
    int t = threadIdx.x;
    for (int i = t; i < KJA * 16; i += 256) {
        int n = i >> 4, k8 = i & 15;
        uint4 v = *(const uint4*)&WT[n * 128 + k8 * 8];
        *(uint4*)&sWT[n * WS + k8 * 8] = v;
    }
    __syncthreads();

    int lane = t & 63;
    int wv = t >> 6;
    int m0 = bid * 128 + wv * 32;
    int l16 = lane & 15;
    int q4 = lane >> 4;

    short8 afr[4][2];
    #pragma unroll
    for (int rt = 0; rt < 2; rt++) {
        int row = m0 + rt * 16 + l16;
        bool vr = row < nRows;
        if (ABF16) {
            const unsigned int* xp = (const unsigned int*)Xv + (size_t)row * 64 + q4 * 4;
            #pragma unroll
            for (int kk = 0; kk < 4; kk++) {
                uint4 u = make_uint4(0u, 0u, 0u, 0u);
                if (vr) u = *(const uint4*)(xp + kk * 16);
                afr[kk][rt] = *(short8*)&u;
            }
        } else {
            const float* xp = (const float*)Xv + (size_t)row * 128 + q4 * 8;
            #pragma unroll
            for (int kk = 0; kk < 4; kk++) {
                float4 a0 = make_float4(0.f, 0.f, 0.f, 0.f), a1 = a0;
                if (vr) {
                    a0 = *(const float4*)(xp + kk * 32);
                    a1 = *(const float4*)(xp + kk * 32 + 4);
                }
                unsigned int u[4];
                u[0] = pk2(a0.x, a0.y); u[1] = pk2(a0.z, a0.w);
                u[2] = pk2(a1.x, a1.y); u[3] = pk2(a1.z, a1.w);
                afr[kk][rt] = *(short8*)u;
            }
        }
    }

    f32x4 acc[2][NT] = {};
    #pragma unroll
    for (int kk = 0; kk < 4; kk++) {
        #pragma unroll
        for (int ct = 0; ct < NT; ct++) {
            int n = ct * 16 + l16;
            short8 bf = *(const short8*)&sWT[n * WS + kk * 32 + q4 * 8];
            #pragma unroll
            for (int rt = 0; rt < 2; rt++)
                acc[rt][ct] = __builtin_amdgcn_mfma_f32_16x16x32_bf16(afr[kk][rt], bf, acc[rt][ct], 0, 0, 0);
        }
    }

    #pragma unroll
    for (int rt = 0; rt < 2; rt++) {
        #pragma unroll
        for (int q = 0; q < 4; q++) {
            int row = m0 + rt * 16 + q4 * 4 + q;
            if (row >= nRows) continue;
            #pragma unroll
            for (int ct = 0; ct < NTS; ct++) {
                int colc = ct * 16 + l16;
                float v = acc[rt][ct][q];
                if (BIAS) v += bias[colc];
                if (ELU_ACT) v = v > 0.f ? v : (__expf(v) - 1.f);
                if (OUTM == 1) {
                    ((unsigned short*)Yv)[(size_t)row * KJ + colc] = f2bf(v);
                } else if (OUTM == 2) {
                    union { _Float16 hf; unsigned short us; } cv;
                    cv.hf = (_Float16)v;
                    ((unsigned short*)Yv)[(size_t)row * KJ + colc] = cv.us;
                } else {
                    ((float*)Yv)[(size_t)row * KJ + colc] = v;
                }
            }
            if (SC_H > 0) {
                if (l16 < 2 * SC_H) {
                    float v = acc[rt][NT - 1][q];    // raw linear score (a pre-scaled)
                    float* dst = (l16 & 1) ? sdn : ssn;
                    dst[row * SC_H + (l16 >> 1)] = v;
                }
            }
        }
    }
}

template <int KJ, int KJA, bool ELU_ACT, bool BIAS, int OUTM, bool ABF16, int SC_H>
__global__ __launch_bounds__(256) void gemm_mfma(const void* __restrict__ Xv,
                                                 const unsigned short* __restrict__ WT,
                                                 const float* __restrict__ bias,
                                                 void* __restrict__ Yv,
                                                 float* __restrict__ ssn,
                                                 float* __restrict__ sdn, int nRows) {
    __shared__ unsigned short sWT[KJA * 136];
    gemm_body<KJ, KJA, ELU_ACT, BIAS, OUTM, ABF16, SC_H>(
        Xv, WT, bias, Yv, ssn, sdn, nRows, blockIdx.x, sWT);
}

// fused: gemm0 (blocks [0,RT)) + scan_block (blocks [RT,RT+NB)). Both depend only on
// hist_repack_k. Branch is block-uniform, so interior __syncthreads are legal; LDS aliased.
__global__ __launch_bounds__(256) void gemm0_scan_k(const float* __restrict__ x,
                                                    const unsigned short* __restrict__ WT0,
                                                    const float* __restrict__ bin,
                                                    unsigned int* __restrict__ hb,
                                                    const int* __restrict__ counts8,
                                                    int* __restrict__ tmp,
                                                    int* __restrict__ bsum,
                                                    int nRows, int n, int RT) {
    __shared__ unsigned short sWT[128 * 136];
    int bid = blockIdx.x;
    if (bid < RT) {
        gemm_body<128, 128, true, true, 1, false, 0>(
            x, WT0, bin, hb, nullptr, nullptr, nRows, bid, sWT);
    } else {
        int* s = (int*)sWT;
        int sb = bid - RT;
        int i = sb * 256 + threadIdx.x;
        int v = 0;
        if (i < n) {
            int c = 0;
            #pragma unroll
            for (int r = 0; r < 8; r++) c += counts8[(size_t)r * n + i];
            v = (c + 7) & ~7;   // round rows up to x8
        }
        s[threadIdx.x] = v;
        __syncthreads();
        for (int d = 1; d < 256; d <<= 1) {
            int t_ = (threadIdx.x >= (unsigned)d) ? s[threadIdx.x - d] : 0;
            __syncthreads();
            s[threadIdx.x] += t_;
            __syncthreads();
        }
        if (i < n) tmp[i] = s[threadIdx.x];
        if (threadIdx.x == 255) bsum[sb] = s[255];
    }
}

// ---------------- edge pass: fp16 hW + v_dot2 aggregation --------------
// One wave per dst row; 16 lanes per row-slice, 4 edge-pair slots (g=lane>>4), each slot
// handles adjacent edges i+2g, i+2g+1 (single dwordx2 scol load). CSR rows padded to x8
// with dummy node (sdst=-1e30 -> w=0, hW row zeroed) so the loop has no validity logic.

template <int DHT, int H, bool ELU_ACT, bool BF16O>
__global__ __launch_bounds__(256) void edge_agg_v(const unsigned int* __restrict__ hW2,
                                                  const float* __restrict__ ssrc,
                                                  const float* __restrict__ sdst,
                                                  const int* __restrict__ off,
                                                  const int* __restrict__ scol,
                                                  void* __restrict__ outv, int nRows) {
    constexpr int FPL = DHT / 16;   // features per lane
    constexpr int UPL = FPL / 2;    // packed uints per lane
    int lane = threadIdx.x & 63;
    int sub = lane & 15;
    int g = lane >> 4;
    int wv = threadIdx.x >> 6;
    int r = __builtin_amdgcn_readfirstlane(blockIdx.x * 4 + wv);
    if (r >= nRows) return;
    int begin = off[r], end = off[r + 1];

    int head = (H == 4) ? (sub >> 2) : 0;
    float ssl = ssrc[r * H + head];

    float acc[FPL] = {};
    float den = 0.f;

    for (int i = begin; i < end; i += 8) {
        int2 cc = *(const int2*)&scol[i + 2 * g];
        int cA = cc.x, cB = cc.y;
        float sdA = sdst[cA * H + head];
        float sdB = sdst[cB * H + head];
        unsigned int hA[UPL], hB[UPL];
        int oA = cA * (DHT / 2) + sub * UPL;
        int oB = cB * (DHT / 2) + sub * UPL;
        if (UPL == 4) {
            *(uint4*)hA = *(const uint4*)&hW2[oA];
            *(uint4*)hB = *(const uint4*)&hW2[oB];
        } else {
            *(uint2*)hA = *(const uint2*)&hW2[oA];
            *(uint2*)hB = *(const uint2*)&hW2[oB];
        }
        float lgA = ssl + sdA;
        float wA = fexp2(fmaxf(lgA, LRELU_ALPHA * lgA));
        float lgB = ssl + sdB;
        float wB = fexp2(fmaxf(lgB, LRELU_ALPHA * lgB));
        den += wA + wB;
        h2v w2 = pkrtz(wA, wB);
        #pragma unroll
        for (int q = 0; q < UPL; q++) {
            acc[2 * q]     = dot2f(pack_lo(hA[q], hB[q]), w2, acc[2 * q]);
            acc[2 * q + 1] = dot2f(pack_hi(hA[q], hB[q]), w2, acc[2 * q + 1]);
        }
    }

    #pragma unroll
    for (int s = 16; s < 64; s <<= 1) {
        den += __shfl_xor(den, s);
        #pragma unroll
        for (int p = 0; p < FPL; p++) acc[p] += __shfl_xor(acc[p], s);
    }
    float inv = den > 0.f ? 1.f / den : 0.f;

    float v[FPL];
    #pragma unroll
    for (int p = 0; p < FPL; p++) {
        float tv = acc[p] * inv;
        if (ELU_ACT) tv = tv > 0.f ? tv : (__expf(tv) - 1.f);
        v[p] = tv;
    }

    if (DHT == 128) {
        if (BF16O)
            ((unsigned int*)outv)[(size_t)r * 64 + sub * 4 + g] = pk2(v[2 * g], v[2 * g + 1]);
        else
            *(float2*)&((float*)outv)[(size_t)r * 128 + sub * 8 + 2 * g] =
                make_float2(v[2 * g], v[2 * g + 1]);
    } else {
        ((float*)outv)[(size_t)r * DHT + sub * FPL + g] = v[g];
    }
}

// ---------------- launcher ----------------

extern "C" void kernel_launch(void* const* d_in, const int* in_sizes, int n_in,
                              void* d_out, int out_size, void* d_ws, size_t ws_size,
                              hipStream_t stream) {
    const float* x    = (const float*)d_in[0];
    const int*   ei   = (const int*)d_in[1];
    const float* Win  = (const float*)d_in[2];
    const float* bin  = (const float*)d_in[3];
    const float* ahid = (const float*)d_in[4];
    const float* Whid = (const float*)d_in[5];
    const float* aout = (const float*)d_in[6];
    const float* Wout = (const float*)d_in[7];
    float* out = (float*)d_out;

    const int N_ = in_sizes[0] / 128;
    const int E_ = in_sizes[1] / 2;

    char* p = (char*)d_ws;
    auto alloc = [&](size_t bytes) {
        char* q = p;
        p += (bytes + 511) & ~(size_t)511;
        return q;
    };
    int* counts8 = (int*)alloc((size_t)N_ * 8 * 4);
    int* base8   = (int*)alloc((size_t)N_ * 8 * 4);
    int* rank    = (int*)alloc((size_t)(E_ + 8) * 4);
    int* tmp     = (int*)alloc((size_t)N_ * 4);
    int* off     = (int*)alloc((size_t)(N_ + 1) * 4);
    int* bsum    = (int*)alloc(4096);
    int* scol    = (int*)alloc((size_t)(E_ + 8 * N_ + 64) * 4);   // padded CSR
    float* ssrcA = (float*)alloc((size_t)(N_ + 1) * 4 * 4);
    float* sdstA = (float*)alloc((size_t)(N_ + 1) * 4 * 4);
    float* ssrcB = (float*)alloc((size_t)(N_ + 1) * 4 * 4);
    float* sdstB = (float*)alloc((size_t)(N_ + 1) * 4 * 4);
    float* ssrcC = (float*)alloc((size_t)(N_ + 1) * 4);
    float* sdstC = (float*)alloc((size_t)(N_ + 1) * 4);
    unsigned int* hb  = (unsigned int*)alloc((size_t)N_ * 64 * 4);        // h  bf16 packed
    unsigned int* hWb = (unsigned int*)alloc((size_t)(N_ + 1) * 64 * 4);  // hW fp16 packed (+dummy row)
    unsigned short* WT0 = (unsigned short*)alloc(128 * 128 * 2);
    unsigned short* WT1 = (unsigned short*)alloc(144 * 128 * 2);
    unsigned short* WT2 = (unsigned short*)alloc(144 * 128 * 2);
    unsigned short* WT3 = (unsigned short*)alloc(80 * 128 * 2);

    int NB  = (N_ + 255) / 256;
    int EB8 = (E_ + 2047) / 2048;    // ILP-8: 8 edges per thread
    int RT  = (N_ + 127) / 128;
    int NW  = (N_ + 3) / 4;

    // CSR by destination (= edge_index[0], the softmax segment key), rows padded to x8
    (void)hipMemsetAsync(counts8, 0, (size_t)N_ * 8 * 4, stream);
    hist_repack_k<<<EB8 + 248, 256, 0, stream>>>(
        ei, counts8, rank, sdstA, sdstB, sdstC, hWb,
        Win, Whid, ahid, Wout, aout, WT0, WT1, WT2, WT3, N_, E_, EB8);
    // gemm0 (input linear + ELU -> h0 bf16) || scan_block
    gemm0_scan_k<<<RT + NB, 256, 0, stream>>>(
        x, WT0, bin, hb, counts8, tmp, bsum, N_, N_, RT);
    scan_sums_k<<<1, 512, 0, stream>>>(bsum, NB);
    finalize_k<<<NB, 256, 0, stream>>>(tmp, bsum, counts8, base8, off, scol, N_, N_);
    scatter8_k<<<EB8, 256, 0, stream>>>(ei, rank, base8, scol, N_, E_);

    // hidden layer 1: [hW0 | scoresA] = h0 @ [Wcat0 | a0] ; aggregate -> h1 bf16
    gemm_mfma<128, 144, false, false, 2, true, 4><<<RT, 256, 0, stream>>>(
        hb, WT1, nullptr, hWb, ssrcA, sdstA, N_);
    edge_agg_v<128, 4, true, true><<<NW, 256, 0, stream>>>(
        hWb, ssrcA, sdstA, off, scol, hb, N_);

    // hidden layer 2: [hW1 | scoresB] = h1 @ [Wcat1 | a1] ; aggregate -> h2 bf16
    gemm_mfma<128, 144, false, false, 2, true, 4><<<RT, 256, 0, stream>>>(
        hb, WT2, nullptr, hWb, ssrcB, sdstB, N_);
    edge_agg_v<128, 4, true, true><<<NW, 256, 0, stream>>>(
        hWb, ssrcB, sdstB, off, scol, hb, N_);

    // output layer: [hW2 | scoresC] = h2 @ [Wout | a_out] ; aggregate -> out fp32
    gemm_mfma<64, 80, false, false, 2, true, 1><<<RT, 256, 0, stream>>>(
        hb, WT3, nullptr, hWb, ssrcC, sdstC, N_);
    edge_agg_v<64, 1, false, false><<<NW, 256, 0, stream>>>(
        hWb, ssrcC, sdstC, off, scol, out, N_);
}

// Round 11
// 442.638 us; speedup vs baseline: 1.1109x; 1.0313x over previous
//
#include <hip/hip_runtime.h>
#include <hip/hip_bf16.h>
#include <cstdint>
#include <cstddef>

#define LRELU_ALPHA 0.2f
#define LOG2E 1.44269504088896f

typedef __attribute__((ext_vector_type(8))) short short8;
typedef __attribute__((ext_vector_type(4))) float f32x4;
typedef _Float16 h2v __attribute__((ext_vector_type(2)));

__device__ __forceinline__ unsigned short f2bf(float f) {
    unsigned int u = __float_as_uint(f);
    unsigned int r = (u + 0x7fffu + ((u >> 16) & 1u)) >> 16;   // RTN-even
    return (unsigned short)r;
}
__device__ __forceinline__ float bf2f(unsigned int lo16) {
    return __uint_as_float(lo16 << 16);
}
__device__ __forceinline__ unsigned int pk2(float a, float b) {
    return (unsigned int)f2bf(a) | ((unsigned int)f2bf(b) << 16);
}
__device__ __forceinline__ float fexp2(float x) {
#if __has_builtin(__builtin_amdgcn_exp2f)
    return __builtin_amdgcn_exp2f(x);
#else
    return __expf(x * 0.69314718056f);
#endif
}
__device__ __forceinline__ h2v pkrtz(float a, float b) {
#if __has_builtin(__builtin_amdgcn_cvt_pkrtz)
    auto r = __builtin_amdgcn_cvt_pkrtz(a, b);   // __fp16 ext_vector(2) on this clang
    union { decltype(r) i; h2v o; } u;
    u.i = r;
    return u.o;
#else
    h2v r; r.x = (_Float16)a; r.y = (_Float16)b; return r;
#endif
}
// pack_lo(a,b) = {lo16: a.lo16, hi16: b.lo16}; pack_hi = same for hi halves
__device__ __forceinline__ unsigned int pack_lo(unsigned int a, unsigned int b) {
#if __has_builtin(__builtin_amdgcn_perm)
    return __builtin_amdgcn_perm(a, b, 0x01000504u);
#else
    return (a & 0xffffu) | (b << 16);
#endif
}
__device__ __forceinline__ unsigned int pack_hi(unsigned int a, unsigned int b) {
#if __has_builtin(__builtin_amdgcn_perm)
    return __builtin_amdgcn_perm(a, b, 0x03020706u);
#else
    return (a >> 16) | (b & 0xffff0000u);
#endif
}
union U32H2 { unsigned int u; h2v h; };
__device__ __forceinline__ float dot2f(unsigned int a, h2v w, float acc) {
    U32H2 c; c.u = a;
#if __has_builtin(__builtin_amdgcn_fdot2)
    return __builtin_amdgcn_fdot2(c.h, w, acc, false);
#else
    return acc + (float)c.h.x * (float)w.x + (float)c.h.y * (float)w.y;
#endif
}

// ---------------- CSR build (padded to x8 per row) ----------------
// Ledger (R5/R6/R7): return-atomics may feed COALESCED stores, never scattered stores.
// Ledger (R9): feature-split fails — half-tables exceed 4MB/XCD L2; edge gather
// FETCH ~227MB @ ~3.6TB/s is this access pattern's floor (R2/R3/R9 all null).

// fused: histogram (blocks [0,EB8)) + weight repack (blocks [EB8,EB8+248)).
__global__ void hist_repack_k(const int* __restrict__ ei, int* __restrict__ counts8,
                              int* __restrict__ rank,
                              float* __restrict__ sdA, float* __restrict__ sdB,
                              float* __restrict__ sdC, unsigned int* __restrict__ hW,
                              const float* __restrict__ Win, const float* __restrict__ Whid,
                              const float* __restrict__ ahid, const float* __restrict__ Wout,
                              const float* __restrict__ aout,
                              unsigned short* __restrict__ W0, unsigned short* __restrict__ W1,
                              unsigned short* __restrict__ W2, unsigned short* __restrict__ W3,
                              int N_, int E_, int EB8) {
    int bid = blockIdx.x;
    if (bid < EB8) {
        int rep = bid & 7;
        int base = (bid * 256 + threadIdx.x) * 8;
        int* cnt = counts8 + (size_t)rep * N_;
        if (base + 8 <= E_) {
            int4 a = *(const int4*)&ei[base];
            int4 b = *(const int4*)&ei[base + 4];
            int rk[8];
            rk[0] = atomicAdd(&cnt[a.x], 1);
            rk[1] = atomicAdd(&cnt[a.y], 1);
            rk[2] = atomicAdd(&cnt[a.z], 1);
            rk[3] = atomicAdd(&cnt[a.w], 1);
            rk[4] = atomicAdd(&cnt[b.x], 1);
            rk[5] = atomicAdd(&cnt[b.y], 1);
            rk[6] = atomicAdd(&cnt[b.z], 1);
            rk[7] = atomicAdd(&cnt[b.w], 1);
            *(int4*)&rank[base]     = make_int4(rk[0], rk[1], rk[2], rk[3]);
            *(int4*)&rank[base + 4] = make_int4(rk[4], rk[5], rk[6], rk[7]);
        } else if (base < E_) {
            for (int j = 0; j < 8 && base + j < E_; j++)
                rank[base + j] = atomicAdd(&cnt[ei[base + j]], 1);
        }
        if (bid == 0) {
            int t = threadIdx.x;
            if (t < 4) { sdA[N_ * 4 + t] = -1e30f; sdB[N_ * 4 + t] = -1e30f; }
            if (t == 4) sdC[N_] = -1e30f;
            if (t >= 32 && t < 64)  hW[(size_t)N_ * 32 + (t - 32)] = 0u;   // DHT=64 dummy
            if (t >= 64 && t < 128) hW[(size_t)N_ * 64 + (t - 64)] = 0u;   // DHT=128 dummy
        }
    } else {
        int i = (bid - EB8) * 256 + threadIdx.x;
        if (i < 16384) {                       // Win [128][128], HD=1
            int n = i >> 7, k = i & 127;
            W0[i] = f2bf(Win[k * 128 + n]);
        } else if (i < 16384 + 2 * 18432) {    // W1/W2: [144][128]
            int j = i - 16384;
            int l = j / 18432;
            int jj = j - l * 18432;
            int n = jj >> 7, k = jj & 127;
            float v;
            if (n < 128) {
                int hd = n >> 5, c = n & 31;
                v = Whid[(size_t)l * 16384 + (hd * 128 + k) * 32 + c];
            } else if (n < 136) {
                int ch = n - 128;               // ch = hd*2+side
                v = ahid[((size_t)l * 8 + ch) * 128 + k] * LOG2E;
            } else {
                v = 0.f;
            }
            (l ? W2 : W1)[jj] = f2bf(v);
        } else if (i < 16384 + 2 * 18432 + 10240) {   // W3: [80][128]
            int j = i - (16384 + 2 * 18432);
            int n = j >> 7, k = j & 127;
            float v;
            if (n < 64)       v = Wout[k * 64 + n];
            else if (n < 66)  v = aout[(n - 64) * 128 + k] * LOG2E;
            else              v = 0.f;
            W3[j] = f2bf(v);
        }
    }
}

// off[i+1], per-replica scatter bases, scol pad-gap fill. Each block computes its own
// exclusive prefix of bsum (<=nb ints, block-reduce) — removes the scan_sums launch.
__global__ void finalize_k(const int* __restrict__ tmp, const int* __restrict__ bsum,
                           const int* __restrict__ counts8, int* __restrict__ base8,
                           int* __restrict__ off, int* __restrict__ scol, int N_, int n) {
    __shared__ int sred[256];
    int t = threadIdx.x;
    int acc = 0;
    for (int j = t; j < (int)blockIdx.x; j += 256) acc += bsum[j];
    sred[t] = acc;
    __syncthreads();
    #pragma unroll
    for (int d = 128; d > 0; d >>= 1) {
        if (t < d) sred[t] += sred[t + d];
        __syncthreads();
    }
    int prefix = sred[0];

    int i = blockIdx.x * 256 + t;
    if (i < n) {
        int end = tmp[i] + prefix;
        off[i + 1] = end;
        int c[8], cnt = 0;
        #pragma unroll
        for (int r = 0; r < 8; r++) { c[r] = counts8[(size_t)r * n + i]; cnt += c[r]; }
        int padded = (cnt + 7) & ~7;
        int pos = end - padded;   // = off[i] (padded sizes are contiguous)
        #pragma unroll
        for (int r = 0; r < 8; r++) { base8[(size_t)r * n + i] = pos; pos += c[r]; }
        // pos == start + cnt; fill pad gap with dummy node
        for (; pos < end; pos++) scol[pos] = N_;
    }
    if (i == 0) off[0] = 0;
}

// ---------------- MFMA GEMM body: Y[n,0:KJ] = act(X @ W + bias); last tile = scores ----
// C/D layout: col=lane&15, row=(lane>>4)*4+reg.

template <int KJ, int KJA, bool ELU_ACT, bool BIAS, int OUTM, bool ABF16, int SC_H>
__device__ __forceinline__ void gemm_body(const void* __restrict__ Xv,
                                          const unsigned short* __restrict__ WT,
                                          const float* __restrict__ bias,
                                          void* __restrict__ Yv,
                                          float* __restrict__ ssn,
                                          float* __restrict__ sdn, int nRows,
                                          int bid, unsigned short* sWT) {
    constexpr int NT = KJA / 16;     // all MFMA col tiles
    constexpr int NTS = KJ / 16;     // stored (hW) col tiles
    constexpr int WS = 136;
    int t = threadIdx.x;
    for (int i = t; i < KJA * 16; i += 256) {
        int n = i >> 4, k8 = i & 15;
        uint4 v = *(const uint4*)&WT[n * 128 + k8 * 8];
        *(uint4*)&sWT[n * WS + k8 * 8] = v;
    }
    __syncthreads();

    int lane = t & 63;
    int wv = t >> 6;
    int m0 = bid * 128 + wv * 32;
    int l16 = lane & 15;
    int q4 = lane >> 4;

    short8 afr[4][2];
    #pragma unroll
    for (int rt = 0; rt < 2; rt++) {
        int row = m0 + rt * 16 + l16;
        bool vr = row < nRows;
        if (ABF16) {
            const unsigned int* xp = (const unsigned int*)Xv + (size_t)row * 64 + q4 * 4;
            #pragma unroll
            for (int kk = 0; kk < 4; kk++) {
                uint4 u = make_uint4(0u, 0u, 0u, 0u);
                if (vr) u = *(const uint4*)(xp + kk * 16);
                afr[kk][rt] = *(short8*)&u;
            }
        } else {
            const float* xp = (const float*)Xv + (size_t)row * 128 + q4 * 8;
            #pragma unroll
            for (int kk = 0; kk < 4; kk++) {
                float4 a0 = make_float4(0.f, 0.f, 0.f, 0.f), a1 = a0;
                if (vr) {
                    a0 = *(const float4*)(xp + kk * 32);
                    a1 = *(const float4*)(xp + kk * 32 + 4);
                }
                unsigned int u[4];
                u[0] = pk2(a0.x, a0.y); u[1] = pk2(a0.z, a0.w);
                u[2] = pk2(a1.x, a1.y); u[3] = pk2(a1.z, a1.w);
                afr[kk][rt] = *(short8*)u;
            }
        }
    }

    f32x4 acc[2][NT] = {};
    #pragma unroll
    for (int kk = 0; kk < 4; kk++) {
        #pragma unroll
        for (int ct = 0; ct < NT; ct++) {
            int n = ct * 16 + l16;
            short8 bf = *(const short8*)&sWT[n * WS + kk * 32 + q4 * 8];
            #pragma unroll
            for (int rt = 0; rt < 2; rt++)
                acc[rt][ct] = __builtin_amdgcn_mfma_f32_16x16x32_bf16(afr[kk][rt], bf, acc[rt][ct], 0, 0, 0);
        }
    }

    #pragma unroll
    for (int rt = 0; rt < 2; rt++) {
        #pragma unroll
        for (int q = 0; q < 4; q++) {
            int row = m0 + rt * 16 + q4 * 4 + q;
            if (row >= nRows) continue;
            #pragma unroll
            for (int ct = 0; ct < NTS; ct++) {
                int colc = ct * 16 + l16;
                float v = acc[rt][ct][q];
                if (BIAS) v += bias[colc];
                if (ELU_ACT) v = v > 0.f ? v : (__expf(v) - 1.f);
                if (OUTM == 1) {
                    ((unsigned short*)Yv)[(size_t)row * KJ + colc] = f2bf(v);
                } else if (OUTM == 2) {
                    union { _Float16 hf; unsigned short us; } cv;
                    cv.hf = (_Float16)v;
                    ((unsigned short*)Yv)[(size_t)row * KJ + colc] = cv.us;
                } else {
                    ((float*)Yv)[(size_t)row * KJ + colc] = v;
                }
            }
            if (SC_H > 0) {
                if (l16 < 2 * SC_H) {
                    float v = acc[rt][NT - 1][q];    // raw linear score (a pre-scaled)
                    float* dst = (l16 & 1) ? sdn : ssn;
                    dst[row * SC_H + (l16 >> 1)] = v;
                }
            }
        }
    }
}

template <int KJ, int KJA, bool ELU_ACT, bool BIAS, int OUTM, bool ABF16, int SC_H>
__global__ __launch_bounds__(256) void gemm_mfma(const void* __restrict__ Xv,
                                                 const unsigned short* __restrict__ WT,
                                                 const float* __restrict__ bias,
                                                 void* __restrict__ Yv,
                                                 float* __restrict__ ssn,
                                                 float* __restrict__ sdn, int nRows) {
    __shared__ unsigned short sWT[KJA * 136];
    gemm_body<KJ, KJA, ELU_ACT, BIAS, OUTM, ABF16, SC_H>(
        Xv, WT, bias, Yv, ssn, sdn, nRows, blockIdx.x, sWT);
}

// fused: gemm0 (blocks [0,RT)) + scan_block (blocks [RT,RT+NB)). Both depend only on
// hist_repack_k. Branch is block-uniform, so interior __syncthreads are legal.
__global__ __launch_bounds__(256) void gemm0_scan_k(const float* __restrict__ x,
                                                    const unsigned short* __restrict__ WT0,
                                                    const float* __restrict__ bin,
                                                    unsigned int* __restrict__ hb,
                                                    const int* __restrict__ counts8,
                                                    int* __restrict__ tmp,
                                                    int* __restrict__ bsum,
                                                    int nRows, int n, int RT) {
    __shared__ unsigned short sWT[128 * 136];
    int bid = blockIdx.x;
    if (bid < RT) {
        gemm_body<128, 128, true, true, 1, false, 0>(
            x, WT0, bin, hb, nullptr, nullptr, nRows, bid, sWT);
    } else {
        int* s = (int*)sWT;
        int sb = bid - RT;
        int i = sb * 256 + threadIdx.x;
        int v = 0;
        if (i < n) {
            int c = 0;
            #pragma unroll
            for (int r = 0; r < 8; r++) c += counts8[(size_t)r * n + i];
            v = (c + 7) & ~7;   // round rows up to x8
        }
        s[threadIdx.x] = v;
        __syncthreads();
        for (int d = 1; d < 256; d <<= 1) {
            int t_ = (threadIdx.x >= (unsigned)d) ? s[threadIdx.x - d] : 0;
            __syncthreads();
            s[threadIdx.x] += t_;
            __syncthreads();
        }
        if (i < n) tmp[i] = s[threadIdx.x];
        if (threadIdx.x == 255) bsum[sb] = s[255];
    }
}

// fused: scatter (blocks [0,EB8)) + gemm1 (blocks [EB8,EB8+RT)). Mutually independent:
// scatter needs finalize; gemm1 needs only h0+WT1. Latency-bound scatter blocks coexist
// with MFMA blocks on the same CUs -> pair costs ~max, not sum.
__global__ __launch_bounds__(256) void scatter_gemm1_k(
        const int* __restrict__ ei, const int* __restrict__ rank,
        const int* __restrict__ base8, int* __restrict__ scol, int N_, int E_, int EB8,
        const unsigned int* __restrict__ hb, const unsigned short* __restrict__ WT1,
        unsigned int* __restrict__ hWb, float* __restrict__ ssrcA,
        float* __restrict__ sdstA, int nRows) {
    __shared__ unsigned short sWT[144 * 136];
    int bid = blockIdx.x;
    if (bid < EB8) {
        int rep = bid & 7;   // SAME e->block mapping as hist blocks of hist_repack_k
        int base = (bid * 256 + threadIdx.x) * 8;
        const int* cb = base8 + (size_t)rep * N_;
        if (base + 8 <= E_) {
            int4 a   = *(const int4*)&ei[base];
            int4 b   = *(const int4*)&ei[base + 4];
            int4 ra  = *(const int4*)&rank[base];
            int4 rb  = *(const int4*)&rank[base + 4];
            int4 ca  = *(const int4*)&ei[E_ + base];
            int4 cb4 = *(const int4*)&ei[E_ + base + 4];
            scol[cb[a.x] + ra.x] = ca.x;
            scol[cb[a.y] + ra.y] = ca.y;
            scol[cb[a.z] + ra.z] = ca.z;
            scol[cb[a.w] + ra.w] = ca.w;
            scol[cb[b.x] + rb.x] = cb4.x;
            scol[cb[b.y] + rb.y] = cb4.y;
            scol[cb[b.z] + rb.z] = cb4.z;
            scol[cb[b.w] + rb.w] = cb4.w;
        } else if (base < E_) {
            for (int j = 0; j < 8 && base + j < E_; j++) {
                int r = ei[base + j];
                scol[cb[r] + rank[base + j]] = ei[E_ + base + j];
            }
        }
    } else {
        gemm_body<128, 144, false, false, 2, true, 4>(
            hb, WT1, nullptr, hWb, ssrcA, sdstA, nRows, bid - EB8, sWT);
    }
}

// ---------------- edge pass: fp16 hW + v_dot2 aggregation --------------
// One wave per dst row; 16 lanes per row-slice, 4 edge-pair slots (g=lane>>4), each slot
// handles adjacent edges i+2g, i+2g+1 (single dwordx2 scol load). CSR rows padded to x8
// with dummy node (sdst=-1e30 -> w=0, hW row zeroed) so the loop has no validity logic.

template <int DHT, int H, bool ELU_ACT, bool BF16O>
__global__ __launch_bounds__(256) void edge_agg_v(const unsigned int* __restrict__ hW2,
                                                  const float* __restrict__ ssrc,
                                                  const float* __restrict__ sdst,
                                                  const int* __restrict__ off,
                                                  const int* __restrict__ scol,
                                                  void* __restrict__ outv, int nRows) {
    constexpr int FPL = DHT / 16;   // features per lane
    constexpr int UPL = FPL / 2;    // packed uints per lane
    int lane = threadIdx.x & 63;
    int sub = lane & 15;
    int g = lane >> 4;
    int wv = threadIdx.x >> 6;
    int r = __builtin_amdgcn_readfirstlane(blockIdx.x * 4 + wv);
    if (r >= nRows) return;
    int begin = off[r], end = off[r + 1];

    int head = (H == 4) ? (sub >> 2) : 0;
    float ssl = ssrc[r * H + head];

    float acc[FPL] = {};
    float den = 0.f;

    for (int i = begin; i < end; i += 8) {
        int2 cc = *(const int2*)&scol[i + 2 * g];
        int cA = cc.x, cB = cc.y;
        float sdA = sdst[cA * H + head];
        float sdB = sdst[cB * H + head];
        unsigned int hA[UPL], hB[UPL];
        int oA = cA * (DHT / 2) + sub * UPL;
        int oB = cB * (DHT / 2) + sub * UPL;
        if (UPL == 4) {
            *(uint4*)hA = *(const uint4*)&hW2[oA];
            *(uint4*)hB = *(const uint4*)&hW2[oB];
        } else {
            *(uint2*)hA = *(const uint2*)&hW2[oA];
            *(uint2*)hB = *(const uint2*)&hW2[oB];
        }
        float lgA = ssl + sdA;
        float wA = fexp2(fmaxf(lgA, LRELU_ALPHA * lgA));
        float lgB = ssl + sdB;
        float wB = fexp2(fmaxf(lgB, LRELU_ALPHA * lgB));
        den += wA + wB;
        h2v w2 = pkrtz(wA, wB);
        #pragma unroll
        for (int q = 0; q < UPL; q++) {
            acc[2 * q]     = dot2f(pack_lo(hA[q], hB[q]), w2, acc[2 * q]);
            acc[2 * q + 1] = dot2f(pack_hi(hA[q], hB[q]), w2, acc[2 * q + 1]);
        }
    }

    #pragma unroll
    for (int s = 16; s < 64; s <<= 1) {
        den += __shfl_xor(den, s);
        #pragma unroll
        for (int p = 0; p < FPL; p++) acc[p] += __shfl_xor(acc[p], s);
    }
    float inv = den > 0.f ? 1.f / den : 0.f;

    float v[FPL];
    #pragma unroll
    for (int p = 0; p < FPL; p++) {
        float tv = acc[p] * inv;
        if (ELU_ACT) tv = tv > 0.f ? tv : (__expf(tv) - 1.f);
        v[p] = tv;
    }

    if (DHT == 128) {
        if (BF16O)
            ((unsigned int*)outv)[(size_t)r * 64 + sub * 4 + g] = pk2(v[2 * g], v[2 * g + 1]);
        else
            *(float2*)&((float*)outv)[(size_t)r * 128 + sub * 8 + 2 * g] =
                make_float2(v[2 * g], v[2 * g + 1]);
    } else {
        ((float*)outv)[(size_t)r * DHT + sub * FPL + g] = v[g];
    }
}

// ---------------- launcher ----------------

extern "C" void kernel_launch(void* const* d_in, const int* in_sizes, int n_in,
                              void* d_out, int out_size, void* d_ws, size_t ws_size,
                              hipStream_t stream) {
    const float* x    = (const float*)d_in[0];
    const int*   ei   = (const int*)d_in[1];
    const float* Win  = (const float*)d_in[2];
    const float* bin  = (const float*)d_in[3];
    const float* ahid = (const float*)d_in[4];
    const float* Whid = (const float*)d_in[5];
    const float* aout = (const float*)d_in[6];
    const float* Wout = (const float*)d_in[7];
    float* out = (float*)d_out;

    const int N_ = in_sizes[0] / 128;
    const int E_ = in_sizes[1] / 2;

    char* p = (char*)d_ws;
    auto alloc = [&](size_t bytes) {
        char* q = p;
        p += (bytes + 511) & ~(size_t)511;
        return q;
    };
    int* counts8 = (int*)alloc((size_t)N_ * 8 * 4);
    int* base8   = (int*)alloc((size_t)N_ * 8 * 4);
    int* rank    = (int*)alloc((size_t)(E_ + 8) * 4);
    int* tmp     = (int*)alloc((size_t)N_ * 4);
    int* off     = (int*)alloc((size_t)(N_ + 1) * 4);
    int* bsum    = (int*)alloc(4096);
    int* scol    = (int*)alloc((size_t)(E_ + 8 * N_ + 64) * 4);   // padded CSR
    float* ssrcA = (float*)alloc((size_t)(N_ + 1) * 4 * 4);
    float* sdstA = (float*)alloc((size_t)(N_ + 1) * 4 * 4);
    float* ssrcB = (float*)alloc((size_t)(N_ + 1) * 4 * 4);
    float* sdstB = (float*)alloc((size_t)(N_ + 1) * 4 * 4);
    float* ssrcC = (float*)alloc((size_t)(N_ + 1) * 4);
    float* sdstC = (float*)alloc((size_t)(N_ + 1) * 4);
    unsigned int* hb  = (unsigned int*)alloc((size_t)N_ * 64 * 4);        // h  bf16 packed
    unsigned int* hWb = (unsigned int*)alloc((size_t)(N_ + 1) * 64 * 4);  // hW fp16 packed (+dummy row)
    unsigned short* WT0 = (unsigned short*)alloc(128 * 128 * 2);
    unsigned short* WT1 = (unsigned short*)alloc(144 * 128 * 2);
    unsigned short* WT2 = (unsigned short*)alloc(144 * 128 * 2);
    unsigned short* WT3 = (unsigned short*)alloc(80 * 128 * 2);

    int NB  = (N_ + 255) / 256;
    int EB8 = (E_ + 2047) / 2048;    // ILP-8: 8 edges per thread
    int RT  = (N_ + 127) / 128;
    int NW  = (N_ + 3) / 4;

    // CSR by destination (= edge_index[0], the softmax segment key), rows padded to x8
    (void)hipMemsetAsync(counts8, 0, (size_t)N_ * 8 * 4, stream);
    hist_repack_k<<<EB8 + 248, 256, 0, stream>>>(
        ei, counts8, rank, sdstA, sdstB, sdstC, hWb,
        Win, Whid, ahid, Wout, aout, WT0, WT1, WT2, WT3, N_, E_, EB8);
    // gemm0 (input linear + ELU -> h0 bf16) || scan_block
    gemm0_scan_k<<<RT + NB, 256, 0, stream>>>(
        x, WT0, bin, hb, counts8, tmp, bsum, N_, N_, RT);
    finalize_k<<<NB, 256, 0, stream>>>(tmp, bsum, counts8, base8, off, scol, N_, N_);
    // scatter || gemm1 ([hW0 | scoresA] = h0 @ [Wcat0 | a0])
    scatter_gemm1_k<<<EB8 + RT, 256, 0, stream>>>(
        ei, rank, base8, scol, N_, E_, EB8, hb, WT1, hWb, ssrcA, sdstA, N_);
    edge_agg_v<128, 4, true, true><<<NW, 256, 0, stream>>>(
        hWb, ssrcA, sdstA, off, scol, hb, N_);

    // hidden layer 2: [hW1 | scoresB] = h1 @ [Wcat1 | a1] ; aggregate -> h2 bf16
    gemm_mfma<128, 144, false, false, 2, true, 4><<<RT, 256, 0, stream>>>(
        hb, WT2, nullptr, hWb, ssrcB, sdstB, N_);
    edge_agg_v<128, 4, true, true><<<NW, 256, 0, stream>>>(
        hWb, ssrcB, sdstB, off, scol, hb, N_);

    // output layer: [hW2 | scoresC] = h2 @ [Wout | a_out] ; aggregate -> out fp32
    gemm_mfma<64, 80, false, false, 2, true, 1><<<RT, 256, 0, stream>>>(
        hb, WT3, nullptr, hWb, ssrcC, sdstC, N_);
    edge_agg_v<64, 1, false, false><<<NW, 256, 0, stream>>>(
        hWb, ssrcC, sdstC, off, scol, out, N_);
}